// Round 1
// baseline (672.755 us; speedup 1.0000x reference)
//
#include <hip/hip_runtime.h>
#include <hip/hip_bf16.h>

// Problem constants
#define Tt   50
#define Dd   64
#define NOUT 100
#define G4   512   // 4*H
#define K0S  72    // a0 LDS stride (64 x-cols + 8 pad)
#define K1P  264   // a1 LDS stride (256 + 8 pad)
#define BM   16    // batch rows per workgroup (grid 256 = 4096/16)

typedef __attribute__((ext_vector_type(8))) short  short8;
typedef __attribute__((ext_vector_type(4))) float  floatx4;

#if __has_builtin(__builtin_amdgcn_exp2f)
#define EXP2(v) __builtin_amdgcn_exp2f(v)
#else
#define EXP2(v) exp2f(v)
#endif
__device__ __forceinline__ float rcp_(float v) { return __builtin_amdgcn_rcpf(v); }
// args pre-scaled by -log2e (sigmoid) / -2log2e (tanh) via weight/bias prescale
__device__ __forceinline__ float fsig2(float u)  { return rcp_(1.0f + EXP2(u)); }
__device__ __forceinline__ float ftanh2(float u) { return fmaf(2.0f, rcp_(1.0f + EXP2(u)), -1.0f); }
#define KN2L2E (-2.8853900817779268f)   // -2*log2(e), for tanh(c) with natural-units c

__device__ __forceinline__ short f2bf(float f) {
    __hip_bfloat16 h = __float2bfloat16(f);
    return *reinterpret_cast<const short*>(&h);
}

// ws layout (bytes):
//  w0f bf16[ 98304] @ 0        (layer0 [Wk0;Wr0] 192x512, frag order f=nt*6+kt, nt=w+8g, PRESCALED)
//  w1f bf16[131072] @ 196608   (layer1 [Wk1;Wr1] 256x512, frag order f=nt*8+kt, PRESCALED)
//  wdf bf16[  8192] @ 458752   (Wd 128x64, frag order f=nt*4+kt, unscaled)
//  b0f f32[512]     @ 475136   (PRESCALED)
//  b1f f32[512]     @ 477184   (PRESCALED)
//  bdf f32[64]      @ 479232   (unscaled)
#define W1F_OFF 196608
#define WDF_OFF 458752
#define B0F_OFF 475136
#define B1F_OFF 477184
#define BDF_OFF 479232

__global__ __launch_bounds__(256) void prep_kernel(
    const float* __restrict__ Wk0, const float* __restrict__ Wr0, const float* __restrict__ b0,
    const float* __restrict__ Wk1, const float* __restrict__ Wr1, const float* __restrict__ b1,
    const float* __restrict__ Wd,  const float* __restrict__ bd,  char* __restrict__ ws)
{
    int idx = blockIdx.x * 256 + threadIdx.x;
    short* w0f = (short*)ws;
    short* w1f = (short*)(ws + W1F_OFF);
    short* wdf = (short*)(ws + WDF_OFF);
    float* b0f = (float*)(ws + B0F_OFF);
    float* b1f = (float*)(ws + B1F_OFF);
    float* bdf = (float*)(ws + BDF_OFF);
    const float NL2E = -1.4426950408889634f;   // -log2(e): i,f,o (sigmoid)
    const float N2L2E = -2.8853900817779268f;  // -2log2(e): g (tanh)

    if (idx < 98304) {
        int f = idx >> 9, r = idx & 511;
        int lane = r >> 3, j = r & 7;
        int nt = f / 6, kt = f - nt * 6;
        int k = kt * 32 + (lane >> 4) * 8 + j;
        int col = nt * 16 + (lane & 15);
        float sc = ((col >> 7) == 2) ? N2L2E : NL2E;
        w0f[idx] = f2bf(sc * ((k < Dd) ? Wk0[k * G4 + col] : Wr0[(k - Dd) * G4 + col]));
    } else if (idx < 229376) {
        int i2 = idx - 98304;
        int f = i2 >> 9, r = i2 & 511;
        int lane = r >> 3, j = r & 7;
        int nt = f >> 3, kt = f & 7;
        int k = kt * 32 + (lane >> 4) * 8 + j;
        int col = nt * 16 + (lane & 15);
        float sc = ((col >> 7) == 2) ? N2L2E : NL2E;
        w1f[i2] = f2bf(sc * ((k < 128) ? Wk1[k * G4 + col] : Wr1[(k - 128) * G4 + col]));
    } else if (idx < 237568) {
        int i2 = idx - 229376;
        int f = i2 >> 9, r = i2 & 511;
        int lane = r >> 3, j = r & 7;
        int nt = f >> 2, kt = f & 3;
        int k = kt * 32 + (lane >> 4) * 8 + j;
        int col = nt * 16 + (lane & 15);
        wdf[i2] = f2bf(Wd[k * Dd + col]);
    } else if (idx < 237568 + 1088) {
        int i2 = idx - 237568;
        if (i2 < 512) {
            float sc = ((i2 >> 7) == 2) ? N2L2E : NL2E;
            b0f[i2] = sc * b0[i2];
        } else if (i2 < 1024) {
            int c = i2 - 512;
            float sc = ((c >> 7) == 2) ? N2L2E : NL2E;
            b1f[c] = sc * b1[c];
        } else bdf[i2 - 1024] = bd[i2 - 1024];
    }
}

// Dynamic LDS layout (bytes):
//  a0[2] @ 0     : 2 × 16*72*2  = 4608   (x/pred tiles; slot0 doubles as AR pred slot)
//  a1[2] @ 4608  : 2 × 16*264*2 = 16896  ([h0'|h1'] tiles, ping-pong by region parity)
//  w0l   @ 21504 : 131072                (W0 pairs p=0..15, [p][wave][512])
//  total 152576 (149 KiB)
#define SM_A1  4608
#define SM_W0  21504
#define SM_TOT 152576
#define A0SZ   1152   // shorts per a0 buffer
#define A1SZ   4224   // shorts per a1 buffer

#define MFMA_B16(A, B, C) __builtin_amdgcn_mfma_f32_16x16x32_bf16((A), (B), (C), 0, 0, 0)

// B-fragment for layer0 pair PP (compile-time constant in unrolled loops)
#define W0FRAG(PP) ((PP) < 16 ? *(const short8*)&w0l[(((PP) * 8 + w) << 9) + lane * 8] \
                              : W0R[(PP) - 16])

// gate block: acc[4] (i,f,g,o rows), cell state CS[4], h' -> BASE[.. + COLOFF + hu]
#define GATES(ACC, CS, BASE, COLOFF)                                                     \
    _Pragma("unroll")                                                                    \
    for (int rr = 0; rr < 4; ++rr) {                                                     \
        float si = fsig2(ACC[0][rr]);                                                    \
        float sf = fsig2(ACC[1][rr]);                                                    \
        float tg = ftanh2(ACC[2][rr]);                                                   \
        float so = fsig2(ACC[3][rr]);                                                    \
        float c_ = fmaf(sf, CS[rr], si * tg);                                            \
        CS[rr] = c_;                                                                     \
        (BASE)[(quad * 4 + rr) * K1P + (COLOFF) + hu] = f2bf(so * ftanh2(c_ * KN2L2E));  \
    }

// grid 256, block 512 (8 waves), 1 block/CU. Wave w owns hidden cols 16w..16w+15.
// Software-pipelined region structure: region r computes L1(r) AND L0(r+1).
// All MFMAs of a region are clustered at the top (L1 first, then L0), so the
// L1 gate VALU issues while the trailing L0 MFMAs drain in the matrix pipe.
// Warm region: 1 barrier. AR region: L0's h0-half stays in phase 1; only the
// 8 x-part (pred-feedback) MFMAs sit after the dense barriers. 3 barriers/AR.
__global__ __launch_bounds__(512, 2) void lstm_kernel(
    const float* __restrict__ x, const char* __restrict__ ws, float* __restrict__ out)
{
    extern __shared__ char smem[];
    short* a0b = (short*)smem;                 // 2 buffers of A0SZ (slot0 = AR pred slot)
    short* a1b = (short*)(smem + SM_A1);       // 2 buffers of A1SZ
    short* w0l = (short*)(smem + SM_W0);

    const short* w0f = (const short*)ws;
    const short* w1f = (const short*)(ws + W1F_OFF);
    const short* wdf = (const short*)(ws + WDF_OFF);
    const float* b0f = (const float*)(ws + B0F_OFF);
    const float* b1f = (const float*)(ws + B1F_OFF);
    const float* bdf = (const float*)(ws + BDF_OFF);

    const int tid  = threadIdx.x;
    const int w    = tid >> 6;        // wave 0..7
    const int lane = tid & 63;
    const int l15  = lane & 15;
    const int quad = lane >> 4;
    const int row0 = blockIdx.x * BM;

    // ---- one-time staging ----
    for (int i = tid; i < 2 * A0SZ; i += 512) a0b[i] = 0;
    for (int i = tid; i < 2 * A1SZ; i += 512) a1b[i] = 0;
    // W0 pairs p<16 -> LDS
    for (int c = tid; c < 8192; c += 512) {       // short8 chunks
        int e8 = c & 63;
        int wv = (c >> 6) & 7;
        int p  = c >> 9;                           // 0..15
        int g = p / 6, kt = p - g * 6;
        const short* src = w0f + ((((g * 8 + wv) * 6) + kt) << 9) + e8 * 8;
        *(short8*)&w0l[((p * 8 + wv) << 9) + e8 * 8] = *(const short8*)src;
    }
    const int colx = tid & 63, rgr = tid >> 6;
    {   // stage x(0) -> a0 slot1 (prologue-only), x(1) -> a0 slot0 (region 0)
        a0b[A0SZ + rgr * K0S + colx]       = f2bf(x[(size_t)(row0 + rgr) * (Tt * Dd) + colx]);
        a0b[A0SZ + (rgr + 8) * K0S + colx] = f2bf(x[(size_t)(row0 + rgr + 8) * (Tt * Dd) + colx]);
        a0b[rgr * K0S + colx]              = f2bf(x[(size_t)(row0 + rgr) * (Tt * Dd) + Dd + colx]);
        a0b[(rgr + 8) * K0S + colx]        = f2bf(x[(size_t)(row0 + rgr + 8) * (Tt * Dd) + Dd + colx]);
    }

    // register-resident weights
    const short* w0rb = w0f + w * 3072 + lane * 8;
    const short* w1rb = w1f + w * 4096 + lane * 8;
    short8 W1R[4][8];
    #pragma unroll
    for (int g = 0; g < 4; ++g)
        #pragma unroll
        for (int kt = 0; kt < 8; ++kt)
            W1R[g][kt] = *(const short8*)(w1rb + g * 32768 + kt * 512);
    short8 W0R[8];   // pairs p = 16..23
    #pragma unroll
    for (int p = 16; p < 24; ++p) {
        int g = p / 6, kt = p - g * 6;
        W0R[p - 16] = *(const short8*)(w0rb + g * 24576 + kt * 512);
    }
    short8 WdR[4];
    if (w < 4) {
        #pragma unroll
        for (int kt = 0; kt < 4; ++kt)
            WdR[kt] = *(const short8*)(wdf + ((w * 4 + kt) << 9) + lane * 8);
    }

    const int hu = w * 16 + l15;
    const float bi0 = b0f[hu], bff0 = b0f[128 + hu], bg0 = b0f[256 + hu], bo0 = b0f[384 + hu];
    const float bi1 = b1f[hu], bff1 = b1f[128 + hu], bg1 = b1f[256 + hu], bo1 = b1f[384 + hu];
    const float bdv = bdf[(w & 3) * 16 + l15];

    float c0s[4] = {0.f, 0.f, 0.f, 0.f};
    float c1s[4] = {0.f, 0.f, 0.f, 0.f};

    __syncthreads();   // staging complete

    // ---- prologue: L0(0) = x(0)@Wk0 + b0 (h0(-1)=0, so skip the h-half) ----
    {
        floatx4 acc0[4];
        acc0[0] = (floatx4){bi0,  bi0,  bi0,  bi0};
        acc0[1] = (floatx4){bff0, bff0, bff0, bff0};
        acc0[2] = (floatx4){bg0,  bg0,  bg0,  bg0};
        acc0[3] = (floatx4){bo0,  bo0,  bo0,  bo0};
        #pragma unroll
        for (int kt = 0; kt < 2; ++kt) {
            short8 af = *(const short8*)&a0b[A0SZ + l15 * K0S + kt * 32 + quad * 8];
            #pragma unroll
            for (int g = 0; g < 4; ++g) {
                const int pp = g * 6 + kt;
                acc0[g] = MFMA_B16(af, W0FRAG(pp), acc0[g]);
            }
        }
        GATES(acc0, c0s, a1b + A1SZ, 0);   // h0'(0) -> a1[1] cols 0..127 (cols 128+ stay 0)
    }
    __syncthreads();   // publish h0'(0)

    // ---- regions r = 0..147: L1(r) + L0(r+1) ----
    // MFMA reads a1[(r+1)&1] = [h0'(r) | h1'(r-1)]; gates write a1[r&1].
    for (int r = 0; r < 148; ++r) {
        short* Rb  = a1b + (((r + 1) & 1) ? A1SZ : 0);
        short* Wb  = a1b + ((r & 1) ? A1SZ : 0);
        short* a0r = a0b + ((r & 1) ? A0SZ : 0);         // x(r+1), warm only
        short* a0w = a0b + (((r + 1) & 1) ? A0SZ : 0);   // x(r+2) staging

        // issue next-x global loads early (hidden under the MFMA cluster)
        float xv0, xv1;
        if (r < 48) {
            xv0 = x[(size_t)(row0 + rgr)     * (Tt * Dd) + (r + 2) * Dd + colx];
            xv1 = x[(size_t)(row0 + rgr + 8) * (Tt * Dd) + (r + 2) * Dd + colx];
        }

        floatx4 acc1[4], acc0[4];
        acc1[0] = (floatx4){bi1,  bi1,  bi1,  bi1};
        acc1[1] = (floatx4){bff1, bff1, bff1, bff1};
        acc1[2] = (floatx4){bg1,  bg1,  bg1,  bg1};
        acc1[3] = (floatx4){bo1,  bo1,  bo1,  bo1};
        acc0[0] = (floatx4){bi0,  bi0,  bi0,  bi0};
        acc0[1] = (floatx4){bff0, bff0, bff0, bff0};
        acc0[2] = (floatx4){bg0,  bg0,  bg0,  bg0};
        acc0[3] = (floatx4){bo0,  bo0,  bo0,  bo0};

        // ---- phase 1a: L1(r) MFMA, all 8 kt (finish acc1 as early as possible) ----
        #pragma unroll
        for (int kt = 0; kt < 8; ++kt) {
            short8 af = *(const short8*)&Rb[l15 * K1P + kt * 32 + quad * 8];
            #pragma unroll
            for (int g = 0; g < 4; ++g)
                acc1[g] = MFMA_B16(af, W1R[g][kt], acc1[g]);
        }
        // ---- phase 1b: L0(r+1) h0-half (kt 2..5 over h0'(r), same cols as L1 kt 0..3) ----
        #pragma unroll
        for (int kt = 2; kt < 6; ++kt) {
            short8 af = *(const short8*)&Rb[l15 * K1P + (kt - 2) * 32 + quad * 8];
            #pragma unroll
            for (int g = 0; g < 4; ++g) {
                const int pp = g * 6 + kt;
                acc0[g] = MFMA_B16(af, W0FRAG(pp), acc0[g]);
            }
        }

        if (r < 49) {
            // ---- warm: finish L0 x-part now, then both gate blocks, one barrier ----
            #pragma unroll
            for (int kt = 0; kt < 2; ++kt) {
                short8 af = *(const short8*)&a0r[l15 * K0S + kt * 32 + quad * 8];
                #pragma unroll
                for (int g = 0; g < 4; ++g) {
                    const int pp = g * 6 + kt;
                    acc0[g] = MFMA_B16(af, W0FRAG(pp), acc0[g]);
                }
            }
            GATES(acc1, c1s, Wb, 128);   // h1'(r)   (overlaps trailing L0 MFMAs)
            GATES(acc0, c0s, Wb, 0);     // h0'(r+1)
            if (r < 48) {
                a0w[rgr * K0S + colx]       = f2bf(xv0);
                a0w[(rgr + 8) * K0S + colx] = f2bf(xv1);
            }
            __syncthreads();   // publish h0'(r+1), h1'(r), x(r+2)
        } else {
            // ---- AR: gates L1, dense feedback, then L0 x-part ----
            GATES(acc1, c1s, Wb, 128);   // h1'(r)  (overlaps L0h drain)
            __syncthreads();             // h1'(r) visible
            if (w < 4) {
                floatx4 ad = (floatx4){bdv, bdv, bdv, bdv};
                #pragma unroll
                for (int kt = 0; kt < 4; ++kt) {
                    short8 a_ = *(const short8*)&Wb[l15 * K1P + 128 + kt * 32 + quad * 8];
                    ad = MFMA_B16(a_, WdR[kt], ad);
                }
                const int s = r - 49;
                #pragma unroll
                for (int rr = 0; rr < 4; ++rr) {
                    float pv = ad[rr];
                    int row = quad * 4 + rr;
                    int col = w * 16 + l15;
                    out[(size_t)(row0 + row) * (NOUT * Dd) + s * Dd + col] = pv;
                    a0b[row * K0S + col] = f2bf(pv);   // pred -> a0 slot 0
                }
            }
            __syncthreads();             // pred visible
            #pragma unroll
            for (int kt = 0; kt < 2; ++kt) {
                short8 af = *(const short8*)&a0b[l15 * K0S + kt * 32 + quad * 8];
                #pragma unroll
                for (int g = 0; g < 4; ++g) {
                    const int pp = g * 6 + kt;
                    acc0[g] = MFMA_B16(af, W0FRAG(pp), acc0[g]);
                }
            }
            GATES(acc0, c0s, Wb, 0);     // h0'(r+1)
            __syncthreads();             // publish h0'(r+1)
        }
    }

    // ---- epilogue: L1(148) + dense(148) (s = 99) ----
    {
        short* Rb = a1b + A1SZ;          // [(148+1)&1] = 1
        short* Wb = a1b;                 // [148&1] = 0
        floatx4 acc1[4];
        acc1[0] = (floatx4){bi1,  bi1,  bi1,  bi1};
        acc1[1] = (floatx4){bff1, bff1, bff1, bff1};
        acc1[2] = (floatx4){bg1,  bg1,  bg1,  bg1};
        acc1[3] = (floatx4){bo1,  bo1,  bo1,  bo1};
        #pragma unroll
        for (int kt = 0; kt < 8; ++kt) {
            short8 af = *(const short8*)&Rb[l15 * K1P + kt * 32 + quad * 8];
            #pragma unroll
            for (int g = 0; g < 4; ++g)
                acc1[g] = MFMA_B16(af, W1R[g][kt], acc1[g]);
        }
        GATES(acc1, c1s, Wb, 128);
        __syncthreads();
        if (w < 4) {
            floatx4 ad = (floatx4){bdv, bdv, bdv, bdv};
            #pragma unroll
            for (int kt = 0; kt < 4; ++kt) {
                short8 a_ = *(const short8*)&Wb[l15 * K1P + 128 + kt * 32 + quad * 8];
                ad = MFMA_B16(a_, WdR[kt], ad);
            }
            #pragma unroll
            for (int rr = 0; rr < 4; ++rr) {
                int row = quad * 4 + rr;
                int col = w * 16 + l15;
                out[(size_t)(row0 + row) * (NOUT * Dd) + 99 * Dd + col] = ad[rr];
            }
        }
    }
}

extern "C" void kernel_launch(void* const* d_in, const int* in_sizes, int n_in,
                              void* d_out, int out_size, void* d_ws, size_t ws_size,
                              hipStream_t stream)
{
    (void)in_sizes; (void)n_in; (void)out_size; (void)ws_size;
    static_assert(SM_TOT <= 160 * 1024, "LDS budget");
    hipFuncSetAttribute(reinterpret_cast<const void*>(lstm_kernel),
                        hipFuncAttributeMaxDynamicSharedMemorySize, SM_TOT);
    prep_kernel<<<933, 256, 0, stream>>>(
        (const float*)d_in[1], (const float*)d_in[2], (const float*)d_in[3],
        (const float*)d_in[4], (const float*)d_in[5], (const float*)d_in[6],
        (const float*)d_in[7], (const float*)d_in[8], (char*)d_ws);
    lstm_kernel<<<256, 512, SM_TOT, stream>>>(
        (const float*)d_in[0], (const char*)d_ws, (float*)d_out);
}

// Round 2
// 479.877 us; speedup vs baseline: 1.4019x; 1.4019x over previous
//
#include <hip/hip_runtime.h>
#include <hip/hip_bf16.h>

// Problem constants
#define Tt   50
#define Dd   64
#define NOUT 100
#define G4   512   // 4*H
#define K0S  72    // a0 LDS stride (64 x-cols + 8 pad)
#define K1P  264   // a1 LDS stride (256 + 8 pad)
#define BM   16    // batch rows per workgroup (grid 256 = 4096/16)

typedef __attribute__((ext_vector_type(8))) short  short8;
typedef __attribute__((ext_vector_type(4))) float  floatx4;

#if __has_builtin(__builtin_amdgcn_exp2f)
#define EXP2(v) __builtin_amdgcn_exp2f(v)
#else
#define EXP2(v) exp2f(v)
#endif
__device__ __forceinline__ float rcp_(float v) { return __builtin_amdgcn_rcpf(v); }
#define KN2L2E (-2.8853900817779268f)   // -2*log2(e), for tanh(c) with natural-units c

// LDS-only barrier: publishes ds_writes without draining vmcnt (out-stores /
// prefetch loads stay in flight across the barrier). All barrier-protected
// data in this kernel lives in LDS. __syncthreads() would force vmcnt(0).
#define BARRIER() asm volatile("s_waitcnt lgkmcnt(0)\n\ts_barrier" ::: "memory")

__device__ __forceinline__ short f2bf(float f) {
    __hip_bfloat16 h = __float2bfloat16(f);
    return *reinterpret_cast<const short*>(&h);
}

// ws layout (bytes):
//  w0f bf16[ 98304] @ 0        (layer0 [Wk0;Wr0] 192x512, frag order f=nt*6+kt, nt=w+8g, PRESCALED)
//  w1f bf16[131072] @ 196608   (layer1 [Wk1;Wr1] 256x512, frag order f=nt*8+kt, PRESCALED)
//  wdf bf16[  8192] @ 458752   (Wd 128x64, frag order f=nt*4+kt, unscaled)
//  b0f f32[512]     @ 475136   (PRESCALED)
//  b1f f32[512]     @ 477184   (PRESCALED)
//  bdf f32[64]      @ 479232   (unscaled)
#define W1F_OFF 196608
#define WDF_OFF 458752
#define B0F_OFF 475136
#define B1F_OFF 477184
#define BDF_OFF 479232

__global__ __launch_bounds__(256) void prep_kernel(
    const float* __restrict__ Wk0, const float* __restrict__ Wr0, const float* __restrict__ b0,
    const float* __restrict__ Wk1, const float* __restrict__ Wr1, const float* __restrict__ b1,
    const float* __restrict__ Wd,  const float* __restrict__ bd,  char* __restrict__ ws)
{
    int idx = blockIdx.x * 256 + threadIdx.x;
    short* w0f = (short*)ws;
    short* w1f = (short*)(ws + W1F_OFF);
    short* wdf = (short*)(ws + WDF_OFF);
    float* b0f = (float*)(ws + B0F_OFF);
    float* b1f = (float*)(ws + B1F_OFF);
    float* bdf = (float*)(ws + BDF_OFF);
    const float NL2E = -1.4426950408889634f;   // -log2(e): i,f,o (sigmoid)
    const float N2L2E = -2.8853900817779268f;  // -2log2(e): g (tanh)

    if (idx < 98304) {
        int f = idx >> 9, r = idx & 511;
        int lane = r >> 3, j = r & 7;
        int nt = f / 6, kt = f - nt * 6;
        int k = kt * 32 + (lane >> 4) * 8 + j;
        int col = nt * 16 + (lane & 15);
        float sc = ((col >> 7) == 2) ? N2L2E : NL2E;
        w0f[idx] = f2bf(sc * ((k < Dd) ? Wk0[k * G4 + col] : Wr0[(k - Dd) * G4 + col]));
    } else if (idx < 229376) {
        int i2 = idx - 98304;
        int f = i2 >> 9, r = i2 & 511;
        int lane = r >> 3, j = r & 7;
        int nt = f >> 3, kt = f & 7;
        int k = kt * 32 + (lane >> 4) * 8 + j;
        int col = nt * 16 + (lane & 15);
        float sc = ((col >> 7) == 2) ? N2L2E : NL2E;
        w1f[i2] = f2bf(sc * ((k < 128) ? Wk1[k * G4 + col] : Wr1[(k - 128) * G4 + col]));
    } else if (idx < 237568) {
        int i2 = idx - 229376;
        int f = i2 >> 9, r = i2 & 511;
        int lane = r >> 3, j = r & 7;
        int nt = f >> 2, kt = f & 3;
        int k = kt * 32 + (lane >> 4) * 8 + j;
        int col = nt * 16 + (lane & 15);
        wdf[i2] = f2bf(Wd[k * Dd + col]);
    } else if (idx < 237568 + 1088) {
        int i2 = idx - 237568;
        if (i2 < 512) {
            float sc = ((i2 >> 7) == 2) ? N2L2E : NL2E;
            b0f[i2] = sc * b0[i2];
        } else if (i2 < 1024) {
            int c = i2 - 512;
            float sc = ((c >> 7) == 2) ? N2L2E : NL2E;
            b1f[c] = sc * b1[c];
        } else bdf[i2 - 1024] = bd[i2 - 1024];
    }
}

// Dynamic LDS layout (bytes):
//  a0[2] @ 0     : 2 × 16*72*2  = 4608   (x/pred tiles, ping-pong by step parity)
//  a1[2] @ 4608  : 2 × 16*264*2 = 16896  (h0 | h1 tiles, ping-pong)
//  w0l   @ 21504 : 131072                (W0 pairs p=0..15, [p][wave][512])
//  total 152576 (149 KiB)
#define SM_A1  4608
#define SM_W0  21504
#define SM_TOT 152576
#define A0SZ   1152   // shorts per a0 buffer
#define A1SZ   4224   // shorts per a1 buffer

#define MFMA_B16(A, B, C) __builtin_amdgcn_mfma_f32_16x16x32_bf16((A), (B), (C), 0, 0, 0)

// gate block, fused-rcp form (3 rcp/row instead of 5; algebraically identical):
//   sig(i)*tanh(g) = (1-Eg) / ((1+Ei)(1+Eg)),  E* = 2^(prescaled pre-activation)
//   sig(o)*tanh(c) = (1-Ec) / ((1+Eo)(1+Ec)),  Ec = e^(-2c)
#define GATES(ACC, CS, BASE, COLOFF)                                                     \
    _Pragma("unroll")                                                                    \
    for (int rr = 0; rr < 4; ++rr) {                                                     \
        float Ei = EXP2(ACC[0][rr]);                                                     \
        float Ef = EXP2(ACC[1][rr]);                                                     \
        float Eg = EXP2(ACC[2][rr]);                                                     \
        float Eo = EXP2(ACC[3][rr]);                                                     \
        float ig = (1.0f - Eg) * rcp_((1.0f + Ei) * (1.0f + Eg));                        \
        float c_ = fmaf(rcp_(1.0f + Ef), CS[rr], ig);                                    \
        CS[rr] = c_;                                                                     \
        float Ec = EXP2(c_ * KN2L2E);                                                    \
        float h_ = (1.0f - Ec) * rcp_((1.0f + Eo) * (1.0f + Ec));                        \
        (BASE)[(quad * 4 + rr) * K1P + (COLOFF) + hu] = f2bf(h_);                        \
    }

// grid 256, block 512 (8 waves), 1 block/CU. Wave w owns hidden cols 16w..16w+15.
// All weights CU-resident (registers are AT the 256/wave cap at this occupancy —
// do NOT add co-live accumulators; round-1 spill cost 38%). Double-buffered
// activations -> 1 barrier/warm step, 3/AR step. Barriers are LDS-only
// (lgkmcnt), so global out-stores never block a barrier.
__global__ __launch_bounds__(512, 2) void lstm_kernel(
    const float* __restrict__ x, const char* __restrict__ ws, float* __restrict__ out)
{
    extern __shared__ char smem[];
    short* a0b = (short*)smem;                 // 2 buffers of A0SZ
    short* a1b = (short*)(smem + SM_A1);       // 2 buffers of A1SZ
    short* w0l = (short*)(smem + SM_W0);

    const short* w0f = (const short*)ws;
    const short* w1f = (const short*)(ws + W1F_OFF);
    const short* wdf = (const short*)(ws + WDF_OFF);
    const float* b0f = (const float*)(ws + B0F_OFF);
    const float* b1f = (const float*)(ws + B1F_OFF);
    const float* bdf = (const float*)(ws + BDF_OFF);

    const int tid  = threadIdx.x;
    const int w    = tid >> 6;        // wave 0..7
    const int lane = tid & 63;
    const int l15  = lane & 15;
    const int quad = lane >> 4;
    const int row0 = blockIdx.x * BM;

    // ---- one-time staging ----
    for (int i = tid; i < 2 * A0SZ; i += 512) a0b[i] = 0;
    for (int i = tid; i < 2 * A1SZ; i += 512) a1b[i] = 0;
    // W0 pairs p<16 -> LDS
    for (int c = tid; c < 8192; c += 512) {       // short8 chunks
        int e8 = c & 63;
        int wv = (c >> 6) & 7;
        int p  = c >> 9;                           // 0..15
        int g = p / 6, kt = p - g * 6;
        const short* src = w0f + ((((g * 8 + wv) * 6) + kt) << 9) + e8 * 8;
        *(short8*)&w0l[((p * 8 + wv) << 9) + e8 * 8] = *(const short8*)src;
    }
    {   // stage x_0 -> a0[0]
        int colx = tid & 63, rg = tid >> 6;
        a0b[rg * K0S + colx]       = f2bf(x[(size_t)(row0 + rg) * (Tt * Dd) + colx]);
        a0b[(rg + 8) * K0S + colx] = f2bf(x[(size_t)(row0 + rg + 8) * (Tt * Dd) + colx]);
    }

    // register-resident weights
    const short* w0rb = w0f + w * 3072 + lane * 8;
    const short* w1rb = w1f + w * 4096 + lane * 8;
    short8 W1R[4][8];
    #pragma unroll
    for (int g = 0; g < 4; ++g)
        #pragma unroll
        for (int kt = 0; kt < 8; ++kt)
            W1R[g][kt] = *(const short8*)(w1rb + g * 32768 + kt * 512);
    short8 W0R[8];   // pairs p = 16..23
    #pragma unroll
    for (int p = 16; p < 24; ++p) {
        int g = p / 6, kt = p - g * 6;
        W0R[p - 16] = *(const short8*)(w0rb + g * 24576 + kt * 512);
    }
    short8 WdR[4];
    if (w < 4) {
        #pragma unroll
        for (int kt = 0; kt < 4; ++kt)
            WdR[kt] = *(const short8*)(wdf + ((w * 4 + kt) << 9) + lane * 8);
    }

    const int hu = w * 16 + l15;
    const float bi0 = b0f[hu], bff0 = b0f[128 + hu], bg0 = b0f[256 + hu], bo0 = b0f[384 + hu];
    const float bi1 = b1f[hu], bff1 = b1f[128 + hu], bg1 = b1f[256 + hu], bo1 = b1f[384 + hu];
    const float bdv = bdf[(w & 3) * 16 + l15];

    float c0s[4] = {0.f, 0.f, 0.f, 0.f};
    float c1s[4] = {0.f, 0.f, 0.f, 0.f};

    const int colx = tid & 63, rg = tid >> 6;

    __syncthreads();   // staging complete (one full sync is fine here)

    for (int step = 0; step < 149; ++step) {
        const int p = step & 1, q = p ^ 1;
        short* a0p = a0b + p * A0SZ;  short* a0q = a0b + q * A0SZ;
        short* a1p = a1b + p * A1SZ;  short* a1q = a1b + q * A1SZ;

        // issue next-x global loads early (consumed at step bottom)
        float xv0, xv1;
        if (step < Tt - 1) {
            xv0 = x[(size_t)(row0 + rg)     * (Tt * Dd) + (step + 1) * Dd + colx];
            xv1 = x[(size_t)(row0 + rg + 8) * (Tt * Dd) + (step + 1) * Dd + colx];
        }

        // ---------- layer 0: A = [x|h0], x from a0[p], h0 from a1[q] ----------
        floatx4 acc[4];
        acc[0] = (floatx4){bi0,  bi0,  bi0,  bi0};
        acc[1] = (floatx4){bff0, bff0, bff0, bff0};
        acc[2] = (floatx4){bg0,  bg0,  bg0,  bg0};
        acc[3] = (floatx4){bo0,  bo0,  bo0,  bo0};

        #pragma unroll
        for (int kt = 0; kt < 6; ++kt) {
            short8 af = (kt < 2)
                ? *(const short8*)&a0p[l15 * K0S + kt * 32 + quad * 8]
                : *(const short8*)&a1q[l15 * K1P + (kt - 2) * 32 + quad * 8];
            #pragma unroll
            for (int g = 0; g < 4; ++g) {
                const int pp = g * 6 + kt;
                short8 bfr = (pp < 16) ? *(const short8*)&w0l[((pp * 8 + w) << 9) + lane * 8]
                                       : W0R[pp - 16];
                acc[g] = MFMA_B16(af, bfr, acc[g]);
            }
        }

        // ---------- gates layer 0 -> h0' into a1[p] cols 0..127 ----------
        GATES(acc, c0s, a1p, 0);

        // stage next x into a0[q] (before the barrier that publishes it)
        if (step < Tt - 1) {
            a0q[rg * K0S + colx]       = f2bf(xv0);
            a0q[(rg + 8) * K0S + colx] = f2bf(xv1);
        }
        BARRIER();   // C: h0' (and next-x) visible

        // ---------- layer 1: A = a1[p] (h0' | h1) ----------
        acc[0] = (floatx4){bi1,  bi1,  bi1,  bi1};
        acc[1] = (floatx4){bff1, bff1, bff1, bff1};
        acc[2] = (floatx4){bg1,  bg1,  bg1,  bg1};
        acc[3] = (floatx4){bo1,  bo1,  bo1,  bo1};

        #pragma unroll
        for (int kt = 0; kt < 8; ++kt) {
            short8 af = *(const short8*)&a1p[l15 * K1P + kt * 32 + quad * 8];
            #pragma unroll
            for (int g = 0; g < 4; ++g)
                acc[g] = MFMA_B16(af, W1R[g][kt], acc[g]);
        }

        // ---------- gates layer 1 -> h1' into a1[q] cols 128..255 ----------
        GATES(acc, c1s, a1q, 128);

        // ---------- dense head (steps >= 49): pred = h1' @ Wd + bd ----------
        if (step >= Tt - 1) {
            BARRIER();   // D: h1' visible
            if (w < 4) {
                floatx4 ad = (floatx4){bdv, bdv, bdv, bdv};
                #pragma unroll
                for (int kt = 0; kt < 4; ++kt) {
                    short8 a_ = *(const short8*)&a1q[l15 * K1P + 128 + kt * 32 + quad * 8];
                    ad = MFMA_B16(a_, WdR[kt], ad);
                }
                int s = step - (Tt - 1);
                #pragma unroll
                for (int r = 0; r < 4; ++r) {
                    float pv = ad[r];
                    int row = quad * 4 + r;
                    int col = w * 16 + l15;
                    out[(size_t)(row0 + row) * (NOUT * Dd) + s * Dd + col] = pv;
                    a0q[row * K0S + col] = f2bf(pv);   // AR feedback for step+1
                }
            }
            BARRIER();   // E: publish pred before next step's L0 reads a0[q]
        }
    }
}

extern "C" void kernel_launch(void* const* d_in, const int* in_sizes, int n_in,
                              void* d_out, int out_size, void* d_ws, size_t ws_size,
                              hipStream_t stream)
{
    (void)in_sizes; (void)n_in; (void)out_size; (void)ws_size;
    static_assert(SM_TOT <= 160 * 1024, "LDS budget");
    hipFuncSetAttribute(reinterpret_cast<const void*>(lstm_kernel),
                        hipFuncAttributeMaxDynamicSharedMemorySize, SM_TOT);
    prep_kernel<<<933, 256, 0, stream>>>(
        (const float*)d_in[1], (const float*)d_in[2], (const float*)d_in[3],
        (const float*)d_in[4], (const float*)d_in[5], (const float*)d_in[6],
        (const float*)d_in[7], (const float*)d_in[8], (char*)d_ws);
    lstm_kernel<<<256, 512, SM_TOT, stream>>>(
        (const float*)d_in[0], (const char*)d_ws, (float*)d_out);
}